// Round 2
// 897.585 us; speedup vs baseline: 1.0621x; 1.0621x over previous
//
#include <hip/hip_runtime.h>
#include <hip/hip_bf16.h>

typedef unsigned short u16;
typedef unsigned int u32;
typedef short v8s __attribute__((ext_vector_type(8)));
typedef float v4f __attribute__((ext_vector_type(4)));

#define NB 16
#define NQ 64
#define NKV 4096
#define QD 768
#define KD 1024
#define NH 12
#define HD 64

__device__ __forceinline__ u16 f2bf(float f) {
  union { float f; u32 u; } c; c.f = f;
  u32 u = c.u;
  u += 0x7FFFu + ((u >> 16) & 1u);  // round-to-nearest-even
  return (u16)(u >> 16);
}
__device__ __forceinline__ u32 pack2(float a, float b) {
  return (u32)f2bf(a) | ((u32)f2bf(b) << 16);
}

// async 16B global->LDS; lds dest = wave-uniform base + lane*16
__device__ __forceinline__ void async16(const void* g, void* l) {
  __builtin_amdgcn_global_load_lds(
      (const __attribute__((address_space(1))) void*)g,
      (__attribute__((address_space(3))) void*)l, 16, 0, 0);
}

// two W (K,N) f32 -> WT (N,K) bf16 transposes in one launch (blockIdx.z picks)
__global__ __launch_bounds__(256) void prep_wT_dual(
    const float* __restrict__ W0, const float* __restrict__ W1,
    u16* __restrict__ T0, u16* __restrict__ T1, int K, int N) {
  __shared__ float tile[32][33];
  const float* W = blockIdx.z ? W1 : W0;
  u16* WT = blockIdx.z ? T1 : T0;
  const int n0 = blockIdx.x * 32, k0 = blockIdx.y * 32;
  const int tr = threadIdx.x >> 5, tc = threadIdx.x & 31;
#pragma unroll
  for (int r = tr; r < 32; r += 8) tile[r][tc] = W[(size_t)(k0 + r) * N + n0 + tc];
  __syncthreads();
#pragma unroll
  for (int r = tr; r < 32; r += 8) WT[(size_t)(n0 + r) * K + k0 + tc] = f2bf(tile[tc][r]);
}

// f32 -> bf16, 8 elements/thread
__global__ __launch_bounds__(256) void conv8(const float* __restrict__ s,
                                             u16* __restrict__ d, int n8) {
  int i = blockIdx.x * 256 + threadIdx.x;
  if (i >= n8) return;
  const float4* sp = (const float4*)s + (size_t)i * 2;
  float4 a = sp[0], b = sp[1];
  uint4 o;
  o.x = pack2(a.x, a.y); o.y = pack2(a.z, a.w);
  o.z = pack2(b.x, b.y); o.w = pack2(b.z, b.w);
  ((uint4*)d)[i] = o;
}

__global__ void concat_bias(const float* __restrict__ a, const float* __restrict__ b,
                            float* __restrict__ o) {
  int i = blockIdx.x * 256 + threadIdx.x;
  if (i < 768) o[i] = a[i];
  else if (i < 1536) o[i] = b[i - 768];
}

// ---------------------------------------------------------------------------
// Small-shape GEMM (kept for q/o projections): C = A[M,K](bf16) @ BT[N,K]^T + bias.
// ---------------------------------------------------------------------------
template<bool OUT_BF16, bool KV_SPLIT>
__global__ __launch_bounds__(256) void gemm_a(
    const u16* __restrict__ A, const u16* __restrict__ BT,
    const float* __restrict__ bias, void* __restrict__ Cp, u16* __restrict__ Vtp,
    int M, int N, int K)
{
  __shared__ __align__(16) u16 As[128][32];  // unpadded (global_load_lds), swizzled
  __shared__ __align__(16) u16 Bs[128][32];
  const int bn0 = blockIdx.x * 128, bm0 = blockIdx.y * 128;
  const int t = threadIdx.x, lane = t & 63, wv = t >> 6;
  const int wm = (wv & 1) * 64, wn = (wv >> 1) * 64;
  const int lm = lane & 15, quad = lane >> 4;
  const int srow = lane >> 2;                              // 4 lanes per 32-u16 row
  const int sc = (((lane & 3) ^ ((srow >> 1) & 3)) * 8);   // swizzled source chunk

  const int r0 = wv * 32, r1 = wv * 32 + 16;
  const u16* aP0 = A  + (size_t)(bm0 + r0 + srow) * K + sc;
  const u16* aP1 = A  + (size_t)(bm0 + r1 + srow) * K + sc;
  const u16* bP0 = BT + (size_t)(bn0 + r0 + srow) * K + sc;
  const u16* bP1 = BT + (size_t)(bn0 + r1 + srow) * K + sc;

  const int swz = (lm >> 1) & 3;

  v4f acc[4][4];
  v4f zero = {0.f, 0.f, 0.f, 0.f};
#pragma unroll
  for (int i = 0; i < 4; ++i)
#pragma unroll
    for (int j = 0; j < 4; ++j) acc[i][j] = zero;

  for (int k0 = 0; k0 < K; k0 += 32) {
    async16(aP0, &As[r0][0]);
    async16(aP1, &As[r1][0]);
    async16(bP0, &Bs[r0][0]);
    async16(bP1, &Bs[r1][0]);
    aP0 += 32; aP1 += 32; bP0 += 32; bP1 += 32;
    __builtin_amdgcn_s_waitcnt(0);
    __syncthreads();
    v8s a[4], b[4];
#pragma unroll
    for (int mt = 0; mt < 4; ++mt)
      a[mt] = *(const v8s*)&As[wm + mt * 16 + lm][(quad ^ swz) * 8];
#pragma unroll
    for (int nt = 0; nt < 4; ++nt)
      b[nt] = *(const v8s*)&Bs[wn + nt * 16 + lm][(quad ^ swz) * 8];
#pragma unroll
    for (int mt = 0; mt < 4; ++mt)
#pragma unroll
      for (int nt = 0; nt < 4; ++nt)
        acc[mt][nt] = __builtin_amdgcn_mfma_f32_16x16x32_bf16(a[mt], b[nt], acc[mt][nt], 0, 0, 0);
    __syncthreads();
  }

  if constexpr (KV_SPLIT) {
    if (bn0 < 768) {
      u16* kp_ = (u16*)Cp;
#pragma unroll
      for (int mt = 0; mt < 4; ++mt)
#pragma unroll
        for (int nt = 0; nt < 4; ++nt) {
          int col = bn0 + wn + nt * 16 + lm;
          float bs = bias[col];
#pragma unroll
          for (int r = 0; r < 4; ++r) {
            int grow = bm0 + wm + mt * 16 + quad * 4 + r;
            kp_[(size_t)grow * 768 + col] = f2bf(acc[mt][nt][r] + bs);
          }
        }
    } else {
#pragma unroll
      for (int mt = 0; mt < 4; ++mt)
#pragma unroll
        for (int nt = 0; nt < 4; ++nt) {
          int col = bn0 + wn + nt * 16 + lm;
          int cv = col - 768;
          float bs = bias[col];
          int grow0 = bm0 + wm + mt * 16 + quad * 4;
          int b_ = grow0 >> 12, kvr = grow0 & 4095;
          uint2 o;
          o.x = pack2(acc[mt][nt][0] + bs, acc[mt][nt][1] + bs);
          o.y = pack2(acc[mt][nt][2] + bs, acc[mt][nt][3] + bs);
          *(uint2*)&Vtp[((size_t)(b_ * 768 + cv)) * 4096 + kvr] = o;
        }
    }
  } else {
#pragma unroll
    for (int mt = 0; mt < 4; ++mt)
#pragma unroll
      for (int nt = 0; nt < 4; ++nt)
#pragma unroll
        for (int r = 0; r < 4; ++r) {
          int row = bm0 + wm + mt * 16 + quad * 4 + r;
          int col = bn0 + wn + nt * 16 + lm;
          float v = acc[mt][nt][r] + bias[col];
          if constexpr (OUT_BF16) ((u16*)Cp)[(size_t)row * N + col] = f2bf(v);
          else                    ((float*)Cp)[(size_t)row * N + col] = v;
        }
  }
}

// ---------------------------------------------------------------------------
// KV projection: 256x256 tile, BK=64, 8 waves (2M x 4N), double-buffered LDS
// (128 KiB), phase-split K-tile with counted waits (loads in flight across
// phase barriers), XOR chunk-swizzle (T2), setprio around MFMA (T5),
// XCD-swizzled grid (T1).
//   A  = kvbf (65536,1024) bf16, BT = WkvT (1536,1024) bf16
//   cols <768 -> kp[grow*768+col]; cols >=768 -> vT[(b*768+cv)*4096+kvr]
// ---------------------------------------------------------------------------
#define KVK 1024
#define KVKT 16     // K-tiles of 64
#define SLOT 32768  // one double-buffer slot: 256 rows * 64 u16 * 2 B

__global__ __launch_bounds__(512, 2) void gemm_kv256(
    const u16* __restrict__ A, const u16* __restrict__ BT,
    const float* __restrict__ bias,
    u16* __restrict__ kp_, u16* __restrict__ vT_)
{
  // [slot][row][64 elems]; row = 128 B; swizzled chunk layout, linear dest for
  // global_load_lds (rule: linear dest + inverse-swz source + swz on read)
  __shared__ __align__(16) u16 As[2][256][64];  // 64 KiB (slot = 32 KiB)
  __shared__ __align__(16) u16 Bs[2][256][64];  // 64 KiB

  // T1: bijective XCD swizzle; 1536 blocks = 8 chunks of 192. Consecutive swz
  // within a chunk walk tile-row-major -> the 6 N-tiles sharing an A-panel
  // (512 KB) run back-to-back on one XCD's L2.
  const int bid = blockIdx.x;
  const int swzb = (bid & 7) * 192 + (bid >> 3);
  const int tn = swzb % 6, tm = swzb / 6;
  const int bn0 = tn * 256, bm0 = tm * 256;

  const int tid = threadIdx.x;
  const int lane = tid & 63, wv = tid >> 6;
  const int lm = lane & 15, quad = lane >> 4;
  const int wrow = wv >> 2, wcol = wv & 3;  // 2 x 4 wave grid; wave out = 128x64

  // --- staging addressing ---------------------------------------------------
  // One round = 512 thr x 16 B = 8 KiB = 64 rows. 4 rounds per matrix per
  // K-tile. Linear LDS byte o = row*128 + chunk*16 with row = r*64 + tid/8,
  // chunk = tid&7. Source pre-swizzled: global chunk = chunk ^ (row&7), so
  // LDS[row][c] holds global[row][c ^ (row&7)] (XOR involution).
  const int srow = tid >> 3;
  const int schunk = (tid & 7) ^ (srow & 7);
  const u16* aS = A  + (size_t)(bm0 + srow) * KVK + schunk * 8;
  const u16* bS = BT + (size_t)(bn0 + srow) * KVK + schunk * 8;
  char* const aD = (char*)&As[0][0][0] + wv * 1024;  // + slot*SLOT + r*8192
  char* const bD = (char*)&Bs[0][0][0] + wv * 1024;

  // --- fragment read addressing (swizzled) ----------------------------------
  // A-frag (mt,ks): row = wrow*128 + mt*16 + lm, global chunk = ks*4+quad,
  // stored at chunk ^ (row&7) = chunk ^ (lm&7). Per 16-lane group the 8
  // distinct chunks spread over all 32 banks -> 2-way aliasing only (free).
  const int c0 = (quad ^ (lm & 7)) * 16;
  const int c1 = ((quad + 4) ^ (lm & 7)) * 16;
  const char* const aR = (const char*)&As[0][0][0] + (wrow * 128 + lm) * 128;
  const char* const bR = (const char*)&Bs[0][0][0] + (wcol * 64 + lm) * 128;

  v4f acc[8][4];
  v4f zero = {0.f, 0.f, 0.f, 0.f};
#pragma unroll
  for (int i = 0; i < 8; ++i)
#pragma unroll
    for (int j = 0; j < 4; ++j) acc[i][j] = zero;

  // prologue: stage tile 0 -> slot 0 (the only uncovered load latency)
#pragma unroll
  for (int r = 0; r < 4; ++r) {
    async16(aS + (size_t)r * (64 * KVK), aD + r * 8192);
    async16(bS + (size_t)r * (64 * KVK), bD + r * 8192);
  }
  aS += 64; bS += 64;
  __syncthreads();  // vmcnt(0)+lgkmcnt(0)+barrier: tile 0 resident

  int soff = 0;  // LDS slot byte offset (0 / SLOT)
#pragma unroll 1
  for (int t = 0; t < KVKT; ++t) {
    const int noff = soff ^ SLOT;
    // T3/T4: issue ALL of tile t+1's 8 loads now -> ~4 phases (~2400 cyc) of
    // MFMA cover HBM latency; drained only at the tile-boundary syncthreads.
    if (t + 1 < KVKT) {
#pragma unroll
      for (int r = 0; r < 4; ++r) {
        async16(aS + (size_t)r * (64 * KVK), aD + noff + r * 8192);
        async16(bS + (size_t)r * (64 * KVK), bD + noff + r * 8192);
      }
      aS += 64; bS += 64;
    }
    // B-fragments once per K-tile (reused by all 4 phases): 8 ds_read_b128
    v8s bf[4][2];
#pragma unroll
    for (int nt = 0; nt < 4; ++nt) {
      const char* bp = bR + soff + nt * 2048;
      bf[nt][0] = *(const v8s*)(bp + c0);
      bf[nt][1] = *(const v8s*)(bp + c1);
    }
    // 4 phases; phase p = 2 M-rows of fragments x all 4 N x K=64 -> 16 MFMA
#pragma unroll
    for (int p = 0; p < 4; ++p) {
      v8s af[2][2];
#pragma unroll
      for (int i = 0; i < 2; ++i) {
        const char* ap = aR + soff + (p * 2 + i) * 2048;
        af[i][0] = *(const v8s*)(ap + c0);
        af[i][1] = *(const v8s*)(ap + c1);
      }
      __builtin_amdgcn_s_barrier();                       // raw: no vmem drain
      asm volatile("s_waitcnt lgkmcnt(0)" ::: "memory");  // own ds_reads done
      __builtin_amdgcn_sched_barrier(0);                  // rule #18: pin MFMA below wait
      __builtin_amdgcn_s_setprio(1);                      // T5
#pragma unroll
      for (int i = 0; i < 2; ++i)
#pragma unroll
        for (int nt = 0; nt < 4; ++nt) {
          acc[p * 2 + i][nt] = __builtin_amdgcn_mfma_f32_16x16x32_bf16(
              af[i][0], bf[nt][0], acc[p * 2 + i][nt], 0, 0, 0);
          acc[p * 2 + i][nt] = __builtin_amdgcn_mfma_f32_16x16x32_bf16(
              af[i][1], bf[nt][1], acc[p * 2 + i][nt], 0, 0, 0);
        }
      __builtin_amdgcn_s_setprio(0);
      __builtin_amdgcn_s_barrier();
    }
    // boundary: full drain (loads issued 4 phases ago -> wait ~free) + fence.
    // After this, all waves' writes to slot noff have landed and all reads of
    // slot soff are complete -> safe to flip and overwrite.
    __syncthreads();
    soff = noff;
  }

  // epilogue: C/D layout col=lm, row=quad*4+r (dtype-independent, m89/m91)
  if (bn0 < 768) {
#pragma unroll
    for (int mt = 0; mt < 8; ++mt)
#pragma unroll
      for (int nt = 0; nt < 4; ++nt) {
        const int col = bn0 + wcol * 64 + nt * 16 + lm;
        const float bs = bias[col];
        const int grow0 = bm0 + wrow * 128 + mt * 16 + quad * 4;
#pragma unroll
        for (int r = 0; r < 4; ++r)
          kp_[(size_t)(grow0 + r) * 768 + col] = f2bf(acc[mt][nt][r] + bs);
      }
  } else {
#pragma unroll
    for (int mt = 0; mt < 8; ++mt)
#pragma unroll
      for (int nt = 0; nt < 4; ++nt) {
        const int col = bn0 + wcol * 64 + nt * 16 + lm;
        const int cv = col - 768;
        const float bs = bias[col];
        const int grow0 = bm0 + wrow * 128 + mt * 16 + quad * 4;
        const int b_ = grow0 >> 12, kvr = grow0 & 4095;
        uint2 o;
        o.x = pack2(acc[mt][nt][0] + bs, acc[mt][nt][1] + bs);
        o.y = pack2(acc[mt][nt][2] + bs, acc[mt][nt][3] + bs);
        *(uint2*)&vT_[((size_t)(b_ * 768 + cv)) * 4096 + kvr] = o;
      }
  }
}

// block = (b, h, 16-row q slab); 4 waves, wave w covers kv rows [w*1024, w*1024+1024)
// partial (m,l,O) combined across waves in LDS at the end.
__global__ __launch_bounds__(256) void attn_k(
    const u16* __restrict__ qp,  // (B*64, 768) bf16
    const u16* __restrict__ kp,  // (B*4096, 768) bf16
    const u16* __restrict__ vT,  // (B*768, 4096) bf16: row b*768+h*64+d, col kv
    u16* __restrict__ xo)        // (B*64, 768) bf16
{
  __shared__ __align__(16) u16 Ps[4][16][40];
  __shared__ float Mw[4][16], Lw[4][16];
  __shared__ float Os[4][16][64];
  const int lane = threadIdx.x & 63, w = threadIdx.x >> 6;
  const int lm = lane & 15, quad = lane >> 4;
  const int blk = blockIdx.x, slab = blk & 3, bh = blk >> 2;
  const int b = bh / NH, h = bh - b * NH;
  const int qr0 = b * NQ + slab * 16;

  const u16* qptr = qp + (size_t)(qr0 + lm) * QD + h * HD + quad * 8;
  v8s aq0 = *(const v8s*)qptr;
  v8s aq1 = *(const v8s*)(qptr + 32);

  const u16* kb = kp + (size_t)b * NKV * QD + h * HD;
  const u16* vb = vT + (size_t)(b * QD + h * HD) * NKV;

  float mst[4], lst[4];
  v4f O[4];
  v4f zero = {0.f, 0.f, 0.f, 0.f};
#pragma unroll
  for (int r = 0; r < 4; ++r) { mst[r] = -INFINITY; lst[r] = 0.f; }
#pragma unroll
  for (int d = 0; d < 4; ++d) O[d] = zero;

  const float scale = 0.125f;

  v8s kf[2][4], vf[2][4];
  auto loadchunk = [&](int j0, int bi) {
    const u16* k0p = kb + (size_t)(j0 + lm) * QD + quad * 8;
    const u16* k1p = kb + (size_t)(j0 + 16 + lm) * QD + quad * 8;
    kf[bi][0] = *(const v8s*)k0p;
    kf[bi][1] = *(const v8s*)(k0p + 32);
    kf[bi][2] = *(const v8s*)k1p;
    kf[bi][3] = *(const v8s*)(k1p + 32);
#pragma unroll
    for (int d = 0; d < 4; ++d)
      vf[bi][d] = *(const v8s*)&vb[(size_t)(d * 16 + lm) * NKV + j0 + quad * 8];
  };
  auto compute = [&](int bi) {
    v4f S0 = zero, S1 = zero;
    S0 = __builtin_amdgcn_mfma_f32_16x16x32_bf16(aq0, kf[bi][0], S0, 0, 0, 0);
    S0 = __builtin_amdgcn_mfma_f32_16x16x32_bf16(aq1, kf[bi][1], S0, 0, 0, 0);
    S1 = __builtin_amdgcn_mfma_f32_16x16x32_bf16(aq0, kf[bi][2], S1, 0, 0, 0);
    S1 = __builtin_amdgcn_mfma_f32_16x16x32_bf16(aq1, kf[bi][3], S1, 0, 0, 0);

    float p0[4], p1[4], rmax[4];
#pragma unroll
    for (int r = 0; r < 4; ++r) {
      p0[r] = S0[r] * scale; p1[r] = S1[r] * scale;
      rmax[r] = fmaxf(p0[r], p1[r]);
    }
#pragma unroll
    for (int off = 1; off <= 8; off <<= 1)
#pragma unroll
      for (int r = 0; r < 4; ++r) rmax[r] = fmaxf(rmax[r], __shfl_xor(rmax[r], off, 64));

    float alpha[4], rsum[4];
#pragma unroll
    for (int r = 0; r < 4; ++r) {
      float mn = fmaxf(mst[r], rmax[r]);
      alpha[r] = __expf(mst[r] - mn);
      p0[r] = __expf(p0[r] - mn);
      p1[r] = __expf(p1[r] - mn);
      mst[r] = mn;
      rsum[r] = p0[r] + p1[r];
    }
#pragma unroll
    for (int off = 1; off <= 8; off <<= 1)
#pragma unroll
      for (int r = 0; r < 4; ++r) rsum[r] += __shfl_xor(rsum[r], off, 64);
#pragma unroll
    for (int r = 0; r < 4; ++r) {
      lst[r] = lst[r] * alpha[r] + rsum[r];
      Ps[w][quad * 4 + r][lm] = f2bf(p0[r]);
      Ps[w][quad * 4 + r][16 + lm] = f2bf(p1[r]);
    }
#pragma unroll
    for (int d = 0; d < 4; ++d)
#pragma unroll
      for (int r = 0; r < 4; ++r) O[d][r] *= alpha[r];
    v8s aP = *(const v8s*)&Ps[w][lm][quad * 8];  // single-wave DS: in-order
#pragma unroll
    for (int d = 0; d < 4; ++d)
      O[d] = __builtin_amdgcn_mfma_f32_16x16x32_bf16(aP, vf[bi][d], O[d], 0, 0, 0);
  };

  const int base = w * 1024;
  loadchunk(base, 0);
  for (int j0 = base; j0 < base + 1024; j0 += 64) {
    loadchunk(j0 + 32, 1);
    compute(0);
    if (j0 + 64 < base + 1024) loadchunk(j0 + 64, 0);
    compute(1);
  }

  // cross-wave online-softmax combine
  if (lm == 0) {
#pragma unroll
    for (int r = 0; r < 4; ++r) {
      Mw[w][quad * 4 + r] = mst[r];
      Lw[w][quad * 4 + r] = lst[r];
    }
  }
  __syncthreads();
#pragma unroll
  for (int r = 0; r < 4; ++r) {
    int row = quad * 4 + r;
    float M = fmaxf(fmaxf(Mw[0][row], Mw[1][row]), fmaxf(Mw[2][row], Mw[3][row]));
    float sc = __expf(mst[r] - M);
#pragma unroll
    for (int d = 0; d < 4; ++d) Os[w][row][d * 16 + lm] = O[d][r] * sc;
  }
  __syncthreads();
#pragma unroll
  for (int i = 0; i < 4; ++i) {
    int row = w * 4 + i;
    float M = fmaxf(fmaxf(Mw[0][row], Mw[1][row]), fmaxf(Mw[2][row], Mw[3][row]));
    float L = Lw[0][row] * __expf(Mw[0][row] - M) + Lw[1][row] * __expf(Mw[1][row] - M)
            + Lw[2][row] * __expf(Mw[2][row] - M) + Lw[3][row] * __expf(Mw[3][row] - M);
    float o = Os[0][row][lane] + Os[1][row][lane] + Os[2][row][lane] + Os[3][row][lane];
    xo[(size_t)(qr0 + row) * QD + h * HD + lane] = f2bf(o / L);
  }
}

extern "C" void kernel_launch(void* const* d_in, const int* in_sizes, int n_in,
                              void* d_out, int out_size, void* d_ws, size_t ws_size,
                              hipStream_t stream) {
  const float* query = (const float*)d_in[0];
  const float* kv    = (const float*)d_in[1];
  const float* Wq    = (const float*)d_in[2];
  const float* bq    = (const float*)d_in[3];
  const float* Wk    = (const float*)d_in[4];
  const float* bk    = (const float*)d_in[5];
  const float* Wv    = (const float*)d_in[6];
  const float* bv    = (const float*)d_in[7];
  const float* Wo    = (const float*)d_in[8];
  const float* bo    = (const float*)d_in[9];
  float* out = (float*)d_out;
  char* ws = (char*)d_ws;

  // ws layout (bytes); total used: 345,774,080
  u16*   WkvT = (u16*)(ws);                   // (1536,1024)      3,145,728
  float* bkv  = (float*)(ws + 3145728);       // 1536 f32             6,144
  u16*   WqT  = (u16*)(ws + 3151872);         // (768,768)        1,179,648
  u16*   WoT  = (u16*)(ws + 4331520);         //                  1,179,648
  u16*   qbf  = (u16*)(ws + 5511168);         // (1024,768)       1,572,864
  u16*   qp   = (u16*)(ws + 7084032);         // (1024,768)       1,572,864
  u16*   xov  = (u16*)(ws + 8656896);         // (1024,768)       1,572,864
  u16*   kp   = (u16*)(ws + 10229760);        // (65536,768)    100,663,296
  u16*   vT   = (u16*)(ws + 110893056);       // (16*768,4096)  100,663,296
  u16*   kvbf = (u16*)(ws + 211556352);       // (65536,1024)   134,217,728

  prep_wT_dual<<<dim3(24, 32, 2), 256, 0, stream>>>(Wk, Wv, WkvT, WkvT + 768 * 1024, KD, QD);
  prep_wT_dual<<<dim3(24, 24, 2), 256, 0, stream>>>(Wq, Wo, WqT, WoT, QD, QD);
  concat_bias<<<6, 256, 0, stream>>>(bk, bv, bkv);
  // full kv f32 -> bf16 (one pass)
  conv8<<<32768, 256, 0, stream>>>(kv, kvbf, NB * NKV * KD / 8);
  // fused k+v projection: 256x256-tile 8-wave phase-pipelined GEMM
  // (65536,1024) @ (1024,1536) -> kp + transposed vT ; 1536 blocks = 6x256 tiles
  gemm_kv256<<<1536, 512, 0, stream>>>(kvbf, WkvT, bkv, kp, vT);
  // q conversion + projection
  conv8<<<384, 256, 0, stream>>>(query, qbf, NB * NQ * QD / 8);
  gemm_a<true, false><<<dim3(6, 8), 256, 0, stream>>>(qbf, WqT, bq, qp, nullptr,
                                                      1024, QD, QD);
  // attention: block=(b,h,slab), 4 waves kv-split + LDS combine
  attn_k<<<NB * NH * 4, 256, 0, stream>>>(qp, kp, vT, xov);
  // output projection -> f32
  gemm_a<false, false><<<dim3(6, 8), 256, 0, stream>>>(xov, WoT, bo, out, nullptr,
                                                       1024, QD, QD);
}

// Round 4
// 885.349 us; speedup vs baseline: 1.0768x; 1.0138x over previous
//
#include <hip/hip_runtime.h>
#include <hip/hip_bf16.h>

typedef unsigned short u16;
typedef unsigned int u32;
typedef short v8s __attribute__((ext_vector_type(8)));
typedef float v4f __attribute__((ext_vector_type(4)));

#define NB 16
#define NQ 64
#define NKV 4096
#define QD 768
#define KD 1024
#define NH 12
#define HD 64

__device__ __forceinline__ u16 f2bf(float f) {
  union { float f; u32 u; } c; c.f = f;
  u32 u = c.u;
  u += 0x7FFFu + ((u >> 16) & 1u);  // round-to-nearest-even
  return (u16)(u >> 16);
}
__device__ __forceinline__ u32 pack2(float a, float b) {
  return (u32)f2bf(a) | ((u32)f2bf(b) << 16);
}

// async 16B global->LDS; lds dest = wave-uniform base + lane*16
__device__ __forceinline__ void async16(const void* g, void* l) {
  __builtin_amdgcn_global_load_lds(
      (const __attribute__((address_space(1))) void*)g,
      (__attribute__((address_space(3))) void*)l, 16, 0, 0);
}

// two W (K,N) f32 -> WT (N,K) bf16 transposes in one launch (blockIdx.z picks)
__global__ __launch_bounds__(256) void prep_wT_dual(
    const float* __restrict__ W0, const float* __restrict__ W1,
    u16* __restrict__ T0, u16* __restrict__ T1, int K, int N) {
  __shared__ float tile[32][33];
  const float* W = blockIdx.z ? W1 : W0;
  u16* WT = blockIdx.z ? T1 : T0;
  const int n0 = blockIdx.x * 32, k0 = blockIdx.y * 32;
  const int tr = threadIdx.x >> 5, tc = threadIdx.x & 31;
#pragma unroll
  for (int r = tr; r < 32; r += 8) tile[r][tc] = W[(size_t)(k0 + r) * N + n0 + tc];
  __syncthreads();
#pragma unroll
  for (int r = tr; r < 32; r += 8) WT[(size_t)(n0 + r) * K + k0 + tc] = f2bf(tile[tc][r]);
}

// f32 -> bf16, 8 elements/thread
__global__ __launch_bounds__(256) void conv8(const float* __restrict__ s,
                                             u16* __restrict__ d, int n8) {
  int i = blockIdx.x * 256 + threadIdx.x;
  if (i >= n8) return;
  const float4* sp = (const float4*)s + (size_t)i * 2;
  float4 a = sp[0], b = sp[1];
  uint4 o;
  o.x = pack2(a.x, a.y); o.y = pack2(a.z, a.w);
  o.z = pack2(b.x, b.y); o.w = pack2(b.z, b.w);
  ((uint4*)d)[i] = o;
}

__global__ void concat_bias(const float* __restrict__ a, const float* __restrict__ b,
                            float* __restrict__ o) {
  int i = blockIdx.x * 256 + threadIdx.x;
  if (i < 768) o[i] = a[i];
  else if (i < 1536) o[i] = b[i - 768];
}

// ---------------------------------------------------------------------------
// Small-shape GEMM (kept for q/o projections): C = A[M,K](bf16) @ BT[N,K]^T + bias.
// ---------------------------------------------------------------------------
template<bool OUT_BF16, bool KV_SPLIT>
__global__ __launch_bounds__(256) void gemm_a(
    const u16* __restrict__ A, const u16* __restrict__ BT,
    const float* __restrict__ bias, void* __restrict__ Cp, u16* __restrict__ Vtp,
    int M, int N, int K)
{
  __shared__ __align__(16) u16 As[128][32];  // unpadded (global_load_lds), swizzled
  __shared__ __align__(16) u16 Bs[128][32];
  const int bn0 = blockIdx.x * 128, bm0 = blockIdx.y * 128;
  const int t = threadIdx.x, lane = t & 63, wv = t >> 6;
  const int wm = (wv & 1) * 64, wn = (wv >> 1) * 64;
  const int lm = lane & 15, quad = lane >> 4;
  const int srow = lane >> 2;                              // 4 lanes per 32-u16 row
  const int sc = (((lane & 3) ^ ((srow >> 1) & 3)) * 8);   // swizzled source chunk

  const int r0 = wv * 32, r1 = wv * 32 + 16;
  const u16* aP0 = A  + (size_t)(bm0 + r0 + srow) * K + sc;
  const u16* aP1 = A  + (size_t)(bm0 + r1 + srow) * K + sc;
  const u16* bP0 = BT + (size_t)(bn0 + r0 + srow) * K + sc;
  const u16* bP1 = BT + (size_t)(bn0 + r1 + srow) * K + sc;

  const int swz = (lm >> 1) & 3;

  v4f acc[4][4];
  v4f zero = {0.f, 0.f, 0.f, 0.f};
#pragma unroll
  for (int i = 0; i < 4; ++i)
#pragma unroll
    for (int j = 0; j < 4; ++j) acc[i][j] = zero;

  for (int k0 = 0; k0 < K; k0 += 32) {
    async16(aP0, &As[r0][0]);
    async16(aP1, &As[r1][0]);
    async16(bP0, &Bs[r0][0]);
    async16(bP1, &Bs[r1][0]);
    aP0 += 32; aP1 += 32; bP0 += 32; bP1 += 32;
    __builtin_amdgcn_s_waitcnt(0);
    __syncthreads();
    v8s a[4], b[4];
#pragma unroll
    for (int mt = 0; mt < 4; ++mt)
      a[mt] = *(const v8s*)&As[wm + mt * 16 + lm][(quad ^ swz) * 8];
#pragma unroll
    for (int nt = 0; nt < 4; ++nt)
      b[nt] = *(const v8s*)&Bs[wn + nt * 16 + lm][(quad ^ swz) * 8];
#pragma unroll
    for (int mt = 0; mt < 4; ++mt)
#pragma unroll
      for (int nt = 0; nt < 4; ++nt)
        acc[mt][nt] = __builtin_amdgcn_mfma_f32_16x16x32_bf16(a[mt], b[nt], acc[mt][nt], 0, 0, 0);
    __syncthreads();
  }

  if constexpr (KV_SPLIT) {
    if (bn0 < 768) {
      u16* kp_ = (u16*)Cp;
#pragma unroll
      for (int mt = 0; mt < 4; ++mt)
#pragma unroll
        for (int nt = 0; nt < 4; ++nt) {
          int col = bn0 + wn + nt * 16 + lm;
          float bs = bias[col];
#pragma unroll
          for (int r = 0; r < 4; ++r) {
            int grow = bm0 + wm + mt * 16 + quad * 4 + r;
            kp_[(size_t)grow * 768 + col] = f2bf(acc[mt][nt][r] + bs);
          }
        }
    } else {
#pragma unroll
      for (int mt = 0; mt < 4; ++mt)
#pragma unroll
        for (int nt = 0; nt < 4; ++nt) {
          int col = bn0 + wn + nt * 16 + lm;
          int cv = col - 768;
          float bs = bias[col];
          int grow0 = bm0 + wm + mt * 16 + quad * 4;
          int b_ = grow0 >> 12, kvr = grow0 & 4095;
          uint2 o;
          o.x = pack2(acc[mt][nt][0] + bs, acc[mt][nt][1] + bs);
          o.y = pack2(acc[mt][nt][2] + bs, acc[mt][nt][3] + bs);
          *(uint2*)&Vtp[((size_t)(b_ * 768 + cv)) * 4096 + kvr] = o;
        }
    }
  } else {
#pragma unroll
    for (int mt = 0; mt < 4; ++mt)
#pragma unroll
      for (int nt = 0; nt < 4; ++nt)
#pragma unroll
        for (int r = 0; r < 4; ++r) {
          int row = bm0 + wm + mt * 16 + quad * 4 + r;
          int col = bn0 + wn + nt * 16 + lm;
          float v = acc[mt][nt][r] + bias[col];
          if constexpr (OUT_BF16) ((u16*)Cp)[(size_t)row * N + col] = f2bf(v);
          else                    ((float*)Cp)[(size_t)row * N + col] = v;
        }
  }
}

// ---------------------------------------------------------------------------
// KV projection v3: 256x256 tile, BK=32, 8 waves (2M x 4N), FOUR LDS slots
// (128 KiB) -> 3-K-tile prefetch depth with counted s_waitcnt vmcnt(8)
// (never 0 in steady state). T1 XCD swizzle + T2 XOR chunk swizzle +
// T5 setprio. Hazard audit:
//   - top-of-tile: own vmcnt wait THEN s_barrier => all waves' tile-t loads
//     resident before any read (closes the cross-wave race).
//   - loads(t+3) target slot (t-1)&3; its last reads finished before the
//     top-of-t barrier every wave crossed before issuing.
//   A  = kvbf (65536,1024) bf16, BT = WkvT (1536,1024) bf16
//   cols <768 -> kp[grow*768+col]; cols >=768 -> vT[(b*768+cv)*4096+kvr]
// ---------------------------------------------------------------------------
#define KVK 1024
#define KT32 32      // K-tiles of 32
#define SLOTB 16384  // one slot: 256 rows * 32 u16 * 2 B

__global__ __launch_bounds__(512, 2) void gemm_kv256(
    const u16* __restrict__ A, const u16* __restrict__ BT,
    const float* __restrict__ bias,
    u16* __restrict__ kp_, u16* __restrict__ vT_)
{
  __shared__ __align__(16) u16 As[4][256][32];  // 64 KiB
  __shared__ __align__(16) u16 Bs[4][256][32];  // 64 KiB

  // T1: bijective XCD swizzle; 1536 blocks = 8 chunks of 192; tn fastest so
  // the 6 N-tiles sharing an A-panel run back-to-back on one XCD's L2.
  const int bid = blockIdx.x;
  const int swzb = (bid & 7) * 192 + (bid >> 3);
  const int tn = swzb % 6, tm = swzb / 6;
  const int bn0 = tn * 256, bm0 = tm * 256;

  const int tid = threadIdx.x;
  const int lane = tid & 63, wv = tid >> 6;
  const int lm = lane & 15, quad = lane >> 4;
  const int wrow = wv >> 2, wcol = wv & 3;  // 2 x 4 wave grid; wave out = 128x64

  // --- staging: 4 thr/row (32 u16 = 64 B), 128 rows/round, 2 rounds/matrix --
  // Linear LDS dest (base + lane*16); source pre-swizzled: stored chunk c
  // holds global chunk c ^ ((row>>1)&3)  [same involution as verified gemm_a]
  const int srow = tid >> 2;                          // 0..127
  const int schunk = (tid & 3) ^ ((srow >> 1) & 3);
  const u16* const aS = A  + (size_t)(bm0 + srow) * KVK + schunk * 8;
  const u16* const bS = BT + (size_t)(bn0 + srow) * KVK + schunk * 8;
  char* const aD = (char*)&As[0][0][0] + wv * 1024;   // + slot*SLOTB + round*8192
  char* const bD = (char*)&Bs[0][0][0] + wv * 1024;

  // --- fragment reads: row = 16-aligned-base + lm => (row>>1)&3 = (lm>>1)&3 --
  const int cA = (quad ^ ((lm >> 1) & 3)) * 16;       // swizzled 16B chunk
  const char* const aR = (const char*)&As[0][0][0] + (wrow * 128 + lm) * 64;
  const char* const bR = (const char*)&Bs[0][0][0] + (wcol * 64 + lm) * 64;

  v4f acc[8][4];
  v4f zero = {0.f, 0.f, 0.f, 0.f};
#pragma unroll
  for (int i = 0; i < 8; ++i)
#pragma unroll
    for (int j = 0; j < 4; ++j) acc[i][j] = zero;

  auto issueA = [&](int t) {
    const u16* s = aS + (size_t)t * 32;
    char* d = aD + (t & 3) * SLOTB;
    async16(s, d);
    async16(s + (size_t)128 * KVK, d + 8192);
  };
  auto issueB = [&](int t) {
    const u16* s = bS + (size_t)t * 32;
    char* d = bD + (t & 3) * SLOTB;
    async16(s, d);
    async16(s + (size_t)128 * KVK, d + 8192);
  };

  // prologue: tiles 0,1,2 in flight (12 loads/wave, tile-major order)
#pragma unroll
  for (int t = 0; t < 3; ++t) { issueA(t); issueB(t); }

#pragma unroll 1
  for (int t = 0; t < KT32; ++t) {
    const int so = (t & 3) * SLOTB;
    // counted wait: own loads of tile t done; up to 8 younger stay in flight
    if (t < KT32 - 2)       asm volatile("s_waitcnt vmcnt(8)" ::: "memory");
    else if (t == KT32 - 2) asm volatile("s_waitcnt vmcnt(4)" ::: "memory");
    else                    asm volatile("s_waitcnt vmcnt(0)" ::: "memory");
    __builtin_amdgcn_sched_barrier(0);
    __builtin_amdgcn_s_barrier();   // collective: every wave's tile-t loads in

    if (t + 3 < KT32) issueA(t + 3);
    // phase 0: B-frags (all 4, reused in phase 1) + A-frags m0..3
    v8s bf[4], af[4];
#pragma unroll
    for (int nt = 0; nt < 4; ++nt) bf[nt] = *(const v8s*)(bR + so + nt * 1024 + cA);
#pragma unroll
    for (int i = 0; i < 4; ++i)    af[i] = *(const v8s*)(aR + so + i * 1024 + cA);
    asm volatile("s_waitcnt lgkmcnt(0)" ::: "memory");
    __builtin_amdgcn_sched_barrier(0);                  // rule #18
    __builtin_amdgcn_s_setprio(1);
#pragma unroll
    for (int i = 0; i < 4; ++i)
#pragma unroll
      for (int nt = 0; nt < 4; ++nt)
        acc[i][nt] = __builtin_amdgcn_mfma_f32_16x16x32_bf16(af[i], bf[nt], acc[i][nt], 0, 0, 0);
    __builtin_amdgcn_s_setprio(0);
    __builtin_amdgcn_s_barrier();   // phase alignment
    if (t + 3 < KT32) issueB(t + 3);
    // phase 1: A-frags m4..7
#pragma unroll
    for (int i = 0; i < 4; ++i)    af[i] = *(const v8s*)(aR + so + (4 + i) * 1024 + cA);
    asm volatile("s_waitcnt lgkmcnt(0)" ::: "memory");
    __builtin_amdgcn_sched_barrier(0);
    __builtin_amdgcn_s_setprio(1);
#pragma unroll
    for (int i = 0; i < 4; ++i)
#pragma unroll
      for (int nt = 0; nt < 4; ++nt)
        acc[4 + i][nt] = __builtin_amdgcn_mfma_f32_16x16x32_bf16(af[i], bf[nt], acc[4 + i][nt], 0, 0, 0);
    __builtin_amdgcn_s_setprio(0);
    // no trailing barrier: next tile's top wait+barrier closes the phase
  }

  // epilogue: C/D layout col=lm, row=quad*4+r (dtype-independent, m89/m91)
  if (bn0 < 768) {
#pragma unroll
    for (int mt = 0; mt < 8; ++mt)
#pragma unroll
      for (int nt = 0; nt < 4; ++nt) {
        const int col = bn0 + wcol * 64 + nt * 16 + lm;
        const float bs = bias[col];
        const int grow0 = bm0 + wrow * 128 + mt * 16 + quad * 4;
#pragma unroll
        for (int r = 0; r < 4; ++r)
          kp_[(size_t)(grow0 + r) * 768 + col] = f2bf(acc[mt][nt][r] + bs);
      }
  } else {
#pragma unroll
    for (int mt = 0; mt < 8; ++mt)
#pragma unroll
      for (int nt = 0; nt < 4; ++nt) {
        const int col = bn0 + wcol * 64 + nt * 16 + lm;
        const int cv = col - 768;
        const float bs = bias[col];
        const int grow0 = bm0 + wrow * 128 + mt * 16 + quad * 4;
        const int b_ = grow0 >> 12, kvr = grow0 & 4095;
        uint2 o;
        o.x = pack2(acc[mt][nt][0] + bs, acc[mt][nt][1] + bs);
        o.y = pack2(acc[mt][nt][2] + bs, acc[mt][nt][3] + bs);
        *(uint2*)&vT_[((size_t)(b_ * 768 + cv)) * 4096 + kvr] = o;
      }
  }
}

// block = (b, h, 16-row q slab); 4 waves, wave w covers kv rows [w*1024, w*1024+1024)
// partial (m,l,O) combined across waves in LDS at the end.
__global__ __launch_bounds__(256) void attn_k(
    const u16* __restrict__ qp,  // (B*64, 768) bf16
    const u16* __restrict__ kp,  // (B*4096, 768) bf16
    const u16* __restrict__ vT,  // (B*768, 4096) bf16: row b*768+h*64+d, col kv
    u16* __restrict__ xo)        // (B*64, 768) bf16
{
  __shared__ __align__(16) u16 Ps[4][16][40];
  __shared__ float Mw[4][16], Lw[4][16];
  __shared__ float Os[4][16][64];
  const int lane = threadIdx.x & 63, w = threadIdx.x >> 6;
  const int lm = lane & 15, quad = lane >> 4;
  const int blk = blockIdx.x, slab = blk & 3, bh = blk >> 2;
  const int b = bh / NH, h = bh - b * NH;
  const int qr0 = b * NQ + slab * 16;

  const u16* qptr = qp + (size_t)(qr0 + lm) * QD + h * HD + quad * 8;
  v8s aq0 = *(const v8s*)qptr;
  v8s aq1 = *(const v8s*)(qptr + 32);

  const u16* kb = kp + (size_t)b * NKV * QD + h * HD;
  const u16* vb = vT + (size_t)(b * QD + h * HD) * NKV;

  float mst[4], lst[4];
  v4f O[4];
  v4f zero = {0.f, 0.f, 0.f, 0.f};
#pragma unroll
  for (int r = 0; r < 4; ++r) { mst[r] = -INFINITY; lst[r] = 0.f; }
#pragma unroll
  for (int d = 0; d < 4; ++d) O[d] = zero;

  const float scale = 0.125f;

  v8s kf[2][4], vf[2][4];
  auto loadchunk = [&](int j0, int bi) {
    const u16* k0p = kb + (size_t)(j0 + lm) * QD + quad * 8;
    const u16* k1p = kb + (size_t)(j0 + 16 + lm) * QD + quad * 8;
    kf[bi][0] = *(const v8s*)k0p;
    kf[bi][1] = *(const v8s*)(k0p + 32);
    kf[bi][2] = *(const v8s*)k1p;
    kf[bi][3] = *(const v8s*)(k1p + 32);
#pragma unroll
    for (int d = 0; d < 4; ++d)
      vf[bi][d] = *(const v8s*)&vb[(size_t)(d * 16 + lm) * NKV + j0 + quad * 8];
  };
  auto compute = [&](int bi) {
    v4f S0 = zero, S1 = zero;
    S0 = __builtin_amdgcn_mfma_f32_16x16x32_bf16(aq0, kf[bi][0], S0, 0, 0, 0);
    S0 = __builtin_amdgcn_mfma_f32_16x16x32_bf16(aq1, kf[bi][1], S0, 0, 0, 0);
    S1 = __builtin_amdgcn_mfma_f32_16x16x32_bf16(aq0, kf[bi][2], S1, 0, 0, 0);
    S1 = __builtin_amdgcn_mfma_f32_16x16x32_bf16(aq1, kf[bi][3], S1, 0, 0, 0);

    float p0[4], p1[4], rmax[4];
#pragma unroll
    for (int r = 0; r < 4; ++r) {
      p0[r] = S0[r] * scale; p1[r] = S1[r] * scale;
      rmax[r] = fmaxf(p0[r], p1[r]);
    }
#pragma unroll
    for (int off = 1; off <= 8; off <<= 1)
#pragma unroll
      for (int r = 0; r < 4; ++r) rmax[r] = fmaxf(rmax[r], __shfl_xor(rmax[r], off, 64));

    float alpha[4], rsum[4];
#pragma unroll
    for (int r = 0; r < 4; ++r) {
      float mn = fmaxf(mst[r], rmax[r]);
      alpha[r] = __expf(mst[r] - mn);
      p0[r] = __expf(p0[r] - mn);
      p1[r] = __expf(p1[r] - mn);
      mst[r] = mn;
      rsum[r] = p0[r] + p1[r];
    }
#pragma unroll
    for (int off = 1; off <= 8; off <<= 1)
#pragma unroll
      for (int r = 0; r < 4; ++r) rsum[r] += __shfl_xor(rsum[r], off, 64);
#pragma unroll
    for (int r = 0; r < 4; ++r) {
      lst[r] = lst[r] * alpha[r] + rsum[r];
      Ps[w][quad * 4 + r][lm] = f2bf(p0[r]);
      Ps[w][quad * 4 + r][16 + lm] = f2bf(p1[r]);
    }
#pragma unroll
    for (int d = 0; d < 4; ++d)
#pragma unroll
      for (int r = 0; r < 4; ++r) O[d][r] *= alpha[r];
    v8s aP = *(const v8s*)&Ps[w][lm][quad * 8];  // single-wave DS: in-order
#pragma unroll
    for (int d = 0; d < 4; ++d)
      O[d] = __builtin_amdgcn_mfma_f32_16x16x32_bf16(aP, vf[bi][d], O[d], 0, 0, 0);
  };

  const int base = w * 1024;
  loadchunk(base, 0);
  for (int j0 = base; j0 < base + 1024; j0 += 64) {
    loadchunk(j0 + 32, 1);
    compute(0);
    if (j0 + 64 < base + 1024) loadchunk(j0 + 64, 0);
    compute(1);
  }

  // cross-wave online-softmax combine
  if (lm == 0) {
#pragma unroll
    for (int r = 0; r < 4; ++r) {
      Mw[w][quad * 4 + r] = mst[r];
      Lw[w][quad * 4 + r] = lst[r];
    }
  }
  __syncthreads();
#pragma unroll
  for (int r = 0; r < 4; ++r) {
    int row = quad * 4 + r;
    float M = fmaxf(fmaxf(Mw[0][row], Mw[1][row]), fmaxf(Mw[2][row], Mw[3][row]));
    float sc = __expf(mst[r] - M);
#pragma unroll
    for (int d = 0; d < 4; ++d) Os[w][row][d * 16 + lm] = O[d][r] * sc;
  }
  __syncthreads();
#pragma unroll
  for (int i = 0; i < 4; ++i) {
    int row = w * 4 + i;
    float M = fmaxf(fmaxf(Mw[0][row], Mw[1][row]), fmaxf(Mw[2][row], Mw[3][row]));
    float L = Lw[0][row] * __expf(Mw[0][row] - M) + Lw[1][row] * __expf(Mw[1][row] - M)
            + Lw[2][row] * __expf(Mw[2][row] - M) + Lw[3][row] * __expf(Mw[3][row] - M);
    float o = Os[0][row][lane] + Os[1][row][lane] + Os[2][row][lane] + Os[3][row][lane];
    xo[(size_t)(qr0 + row) * QD + h * HD + lane] = f2bf(o / L);
  }
}

extern "C" void kernel_launch(void* const* d_in, const int* in_sizes, int n_in,
                              void* d_out, int out_size, void* d_ws, size_t ws_size,
                              hipStream_t stream) {
  const float* query = (const float*)d_in[0];
  const float* kv    = (const float*)d_in[1];
  const float* Wq    = (const float*)d_in[2];
  const float* bq    = (const float*)d_in[3];
  const float* Wk    = (const float*)d_in[4];
  const float* bk    = (const float*)d_in[5];
  const float* Wv    = (const float*)d_in[6];
  const float* bv    = (const float*)d_in[7];
  const float* Wo    = (const float*)d_in[8];
  const float* bo    = (const float*)d_in[9];
  float* out = (float*)d_out;
  char* ws = (char*)d_ws;

  // ws layout (bytes); total used: 345,774,080
  u16*   WkvT = (u16*)(ws);                   // (1536,1024)      3,145,728
  float* bkv  = (float*)(ws + 3145728);       // 1536 f32             6,144
  u16*   WqT  = (u16*)(ws + 3151872);         // (768,768)        1,179,648
  u16*   WoT  = (u16*)(ws + 4331520);         //                  1,179,648
  u16*   qbf  = (u16*)(ws + 5511168);         // (1024,768)       1,572,864
  u16*   qp   = (u16*)(ws + 7084032);         // (1024,768)       1,572,864
  u16*   xov  = (u16*)(ws + 8656896);         // (1024,768)       1,572,864
  u16*   kp   = (u16*)(ws + 10229760);        // (65536,768)    100,663,296
  u16*   vT   = (u16*)(ws + 110893056);       // (16*768,4096)  100,663,296
  u16*   kvbf = (u16*)(ws + 211556352);       // (65536,1024)   134,217,728

  prep_wT_dual<<<dim3(24, 32, 2), 256, 0, stream>>>(Wk, Wv, WkvT, WkvT + 768 * 1024, KD, QD);
  prep_wT_dual<<<dim3(24, 24, 2), 256, 0, stream>>>(Wq, Wo, WqT, WoT, QD, QD);
  concat_bias<<<6, 256, 0, stream>>>(bk, bv, bkv);
  // full kv f32 -> bf16 (one pass)
  conv8<<<32768, 256, 0, stream>>>(kv, kvbf, NB * NKV * KD / 8);
  // fused k+v projection: 256x256-tile, 4-slot deep-pipelined GEMM
  // (65536,1024) @ (1024,1536) -> kp + transposed vT ; 1536 blocks = 6x256 tiles
  gemm_kv256<<<1536, 512, 0, stream>>>(kvbf, WkvT, bkv, kp, vT);
  // q conversion + projection
  conv8<<<384, 256, 0, stream>>>(query, qbf, NB * NQ * QD / 8);
  gemm_a<true, false><<<dim3(6, 8), 256, 0, stream>>>(qbf, WqT, bq, qp, nullptr,
                                                      1024, QD, QD);
  // attention: block=(b,h,slab), 4 waves kv-split + LDS combine
  attn_k<<<NB * NH * 4, 256, 0, stream>>>(qp, kp, vT, xov);
  // output projection -> f32
  gemm_a<false, false><<<dim3(6, 8), 256, 0, stream>>>(xov, WoT, bo, out, nullptr,
                                                       1024, QD, QD);
}

// Round 5
// 835.294 us; speedup vs baseline: 1.1413x; 1.0599x over previous
//
#include <hip/hip_runtime.h>
#include <hip/hip_bf16.h>

typedef unsigned short u16;
typedef unsigned int u32;
typedef short v8s __attribute__((ext_vector_type(8)));
typedef float v4f __attribute__((ext_vector_type(4)));

#define NB 16
#define NQ 64
#define NKV 4096
#define QD 768
#define KD 1024
#define NH 12
#define HD 64

__device__ __forceinline__ u16 f2bf(float f) {
  union { float f; u32 u; } c; c.f = f;
  u32 u = c.u;
  u += 0x7FFFu + ((u >> 16) & 1u);  // round-to-nearest-even
  return (u16)(u >> 16);
}
__device__ __forceinline__ u32 pack2(float a, float b) {
  return (u32)f2bf(a) | ((u32)f2bf(b) << 16);
}

// async 16B global->LDS; lds dest = wave-uniform base + lane*16
__device__ __forceinline__ void async16(const void* g, void* l) {
  __builtin_amdgcn_global_load_lds(
      (const __attribute__((address_space(1))) void*)g,
      (__attribute__((address_space(3))) void*)l, 16, 0, 0);
}

// two W (K,N) f32 -> WT (N,K) bf16 transposes in one launch (blockIdx.z picks)
__global__ __launch_bounds__(256) void prep_wT_dual(
    const float* __restrict__ W0, const float* __restrict__ W1,
    u16* __restrict__ T0, u16* __restrict__ T1, int K, int N) {
  __shared__ float tile[32][33];
  const float* W = blockIdx.z ? W1 : W0;
  u16* WT = blockIdx.z ? T1 : T0;
  const int n0 = blockIdx.x * 32, k0 = blockIdx.y * 32;
  const int tr = threadIdx.x >> 5, tc = threadIdx.x & 31;
#pragma unroll
  for (int r = tr; r < 32; r += 8) tile[r][tc] = W[(size_t)(k0 + r) * N + n0 + tc];
  __syncthreads();
#pragma unroll
  for (int r = tr; r < 32; r += 8) WT[(size_t)(n0 + r) * K + k0 + tc] = f2bf(tile[tc][r]);
}

// f32 -> bf16, 8 elements/thread
__global__ __launch_bounds__(256) void conv8(const float* __restrict__ s,
                                             u16* __restrict__ d, int n8) {
  int i = blockIdx.x * 256 + threadIdx.x;
  if (i >= n8) return;
  const float4* sp = (const float4*)s + (size_t)i * 2;
  float4 a = sp[0], b = sp[1];
  uint4 o;
  o.x = pack2(a.x, a.y); o.y = pack2(a.z, a.w);
  o.z = pack2(b.x, b.y); o.w = pack2(b.z, b.w);
  ((uint4*)d)[i] = o;
}

__global__ void concat_bias(const float* __restrict__ a, const float* __restrict__ b,
                            float* __restrict__ o) {
  int i = blockIdx.x * 256 + threadIdx.x;
  if (i < 768) o[i] = a[i];
  else if (i < 1536) o[i] = b[i - 768];
}

// ---------------------------------------------------------------------------
// Small-shape GEMM (kept for q/o projections): C = A[M,K](bf16) @ BT[N,K]^T + bias.
// ---------------------------------------------------------------------------
template<bool OUT_BF16, bool KV_SPLIT>
__global__ __launch_bounds__(256) void gemm_a(
    const u16* __restrict__ A, const u16* __restrict__ BT,
    const float* __restrict__ bias, void* __restrict__ Cp, u16* __restrict__ Vtp,
    int M, int N, int K)
{
  __shared__ __align__(16) u16 As[128][32];  // unpadded (global_load_lds), swizzled
  __shared__ __align__(16) u16 Bs[128][32];
  const int bn0 = blockIdx.x * 128, bm0 = blockIdx.y * 128;
  const int t = threadIdx.x, lane = t & 63, wv = t >> 6;
  const int wm = (wv & 1) * 64, wn = (wv >> 1) * 64;
  const int lm = lane & 15, quad = lane >> 4;
  const int srow = lane >> 2;                              // 4 lanes per 32-u16 row
  const int sc = (((lane & 3) ^ ((srow >> 1) & 3)) * 8);   // swizzled source chunk

  const int r0 = wv * 32, r1 = wv * 32 + 16;
  const u16* aP0 = A  + (size_t)(bm0 + r0 + srow) * K + sc;
  const u16* aP1 = A  + (size_t)(bm0 + r1 + srow) * K + sc;
  const u16* bP0 = BT + (size_t)(bn0 + r0 + srow) * K + sc;
  const u16* bP1 = BT + (size_t)(bn0 + r1 + srow) * K + sc;

  const int swz = (lm >> 1) & 3;

  v4f acc[4][4];
  v4f zero = {0.f, 0.f, 0.f, 0.f};
#pragma unroll
  for (int i = 0; i < 4; ++i)
#pragma unroll
    for (int j = 0; j < 4; ++j) acc[i][j] = zero;

  for (int k0 = 0; k0 < K; k0 += 32) {
    async16(aP0, &As[r0][0]);
    async16(aP1, &As[r1][0]);
    async16(bP0, &Bs[r0][0]);
    async16(bP1, &Bs[r1][0]);
    aP0 += 32; aP1 += 32; bP0 += 32; bP1 += 32;
    __builtin_amdgcn_s_waitcnt(0);
    __syncthreads();
    v8s a[4], b[4];
#pragma unroll
    for (int mt = 0; mt < 4; ++mt)
      a[mt] = *(const v8s*)&As[wm + mt * 16 + lm][(quad ^ swz) * 8];
#pragma unroll
    for (int nt = 0; nt < 4; ++nt)
      b[nt] = *(const v8s*)&Bs[wn + nt * 16 + lm][(quad ^ swz) * 8];
#pragma unroll
    for (int mt = 0; mt < 4; ++mt)
#pragma unroll
      for (int nt = 0; nt < 4; ++nt)
        acc[mt][nt] = __builtin_amdgcn_mfma_f32_16x16x32_bf16(a[mt], b[nt], acc[mt][nt], 0, 0, 0);
    __syncthreads();
  }

  if constexpr (KV_SPLIT) {
    if (bn0 < 768) {
      u16* kp_ = (u16*)Cp;
#pragma unroll
      for (int mt = 0; mt < 4; ++mt)
#pragma unroll
        for (int nt = 0; nt < 4; ++nt) {
          int col = bn0 + wn + nt * 16 + lm;
          float bs = bias[col];
#pragma unroll
          for (int r = 0; r < 4; ++r) {
            int grow = bm0 + wm + mt * 16 + quad * 4 + r;
            kp_[(size_t)grow * 768 + col] = f2bf(acc[mt][nt][r] + bs);
          }
        }
    } else {
#pragma unroll
      for (int mt = 0; mt < 4; ++mt)
#pragma unroll
        for (int nt = 0; nt < 4; ++nt) {
          int col = bn0 + wn + nt * 16 + lm;
          int cv = col - 768;
          float bs = bias[col];
          int grow0 = bm0 + wm + mt * 16 + quad * 4;
          int b_ = grow0 >> 12, kvr = grow0 & 4095;
          uint2 o;
          o.x = pack2(acc[mt][nt][0] + bs, acc[mt][nt][1] + bs);
          o.y = pack2(acc[mt][nt][2] + bs, acc[mt][nt][3] + bs);
          *(uint2*)&Vtp[((size_t)(b_ * 768 + cv)) * 4096 + kvr] = o;
        }
    }
  } else {
#pragma unroll
    for (int mt = 0; mt < 4; ++mt)
#pragma unroll
      for (int nt = 0; nt < 4; ++nt)
#pragma unroll
        for (int r = 0; r < 4; ++r) {
          int row = bm0 + wm + mt * 16 + quad * 4 + r;
          int col = bn0 + wn + nt * 16 + lm;
          float v = acc[mt][nt][r] + bias[col];
          if constexpr (OUT_BF16) ((u16*)Cp)[(size_t)row * N + col] = f2bf(v);
          else                    ((float*)Cp)[(size_t)row * N + col] = v;
        }
  }
}

// ---------------------------------------------------------------------------
// KV projection v4: 256x256 tile, BK=32, 8 waves (2M x 4N), FOUR LDS slots
// (128 KiB), 3-tile-deep counted-vmcnt prefetch (vmcnt(8), never 0 steady).
// v4 change vs v3 (which measured 322 us, MfmaUtil 27%): intra-tile fine
// interleave -- all 12 ds_reads issued up front in pinned order, counted
// lgkmcnt(4) covers only cluster-1 operands, af[4..7] latency hides under
// MFMA cluster 1, mid-tile barrier removed. One barrier + one vmcnt per tile.
//   A  = kvbf (65536,1024) bf16, BT = WkvT (1536,1024) bf16
//   cols <768 -> kp[grow*768+col]; cols >=768 -> vT[(b*768+cv)*4096+kvr]
// ---------------------------------------------------------------------------
#define KVK 1024
#define KT32 32      // K-tiles of 32
#define SLOTB 16384  // one slot: 256 rows * 32 u16 * 2 B

__global__ __launch_bounds__(512, 2) void gemm_kv256(
    const u16* __restrict__ A, const u16* __restrict__ BT,
    const float* __restrict__ bias,
    u16* __restrict__ kp_, u16* __restrict__ vT_)
{
  __shared__ __align__(16) u16 As[4][256][32];  // 64 KiB
  __shared__ __align__(16) u16 Bs[4][256][32];  // 64 KiB

  // T1: bijective XCD swizzle; 1536 blocks = 8 chunks of 192; tn fastest so
  // the 6 N-tiles sharing an A-panel run back-to-back on one XCD's L2.
  const int bid = blockIdx.x;
  const int swzb = (bid & 7) * 192 + (bid >> 3);
  const int tn = swzb % 6, tm = swzb / 6;
  const int bn0 = tn * 256, bm0 = tm * 256;

  const int tid = threadIdx.x;
  const int lane = tid & 63, wv = tid >> 6;
  const int lm = lane & 15, quad = lane >> 4;
  const int wrow = wv >> 2, wcol = wv & 3;  // 2 x 4 wave grid; wave out = 128x64

  // --- staging: 4 thr/row (32 u16 = 64 B), 128 rows/round, 2 rounds/matrix --
  // Linear LDS dest (base + lane*16); source pre-swizzled: stored chunk c
  // holds global chunk c ^ ((row>>1)&3)  [same involution as verified gemm_a]
  const int srow = tid >> 2;                          // 0..127
  const int schunk = (tid & 3) ^ ((srow >> 1) & 3);
  const u16* const aS = A  + (size_t)(bm0 + srow) * KVK + schunk * 8;
  const u16* const bS = BT + (size_t)(bn0 + srow) * KVK + schunk * 8;
  char* const aD = (char*)&As[0][0][0] + wv * 1024;   // + slot*SLOTB + round*8192
  char* const bD = (char*)&Bs[0][0][0] + wv * 1024;

  // --- fragment reads: row = 16-aligned-base + lm => (row>>1)&3 = (lm>>1)&3 --
  const int cA = (quad ^ ((lm >> 1) & 3)) * 16;       // swizzled 16B chunk
  const char* const aR = (const char*)&As[0][0][0] + (wrow * 128 + lm) * 64;
  const char* const bR = (const char*)&Bs[0][0][0] + (wcol * 64 + lm) * 64;

  v4f acc[8][4];
  v4f zero = {0.f, 0.f, 0.f, 0.f};
#pragma unroll
  for (int i = 0; i < 8; ++i)
#pragma unroll
    for (int j = 0; j < 4; ++j) acc[i][j] = zero;

  auto issueA = [&](int t) {
    const u16* s = aS + (size_t)t * 32;
    char* d = aD + (t & 3) * SLOTB;
    async16(s, d);
    async16(s + (size_t)128 * KVK, d + 8192);
  };
  auto issueB = [&](int t) {
    const u16* s = bS + (size_t)t * 32;
    char* d = bD + (t & 3) * SLOTB;
    async16(s, d);
    async16(s + (size_t)128 * KVK, d + 8192);
  };

  // prologue: tiles 0,1,2 in flight (12 loads/wave, tile-major order)
#pragma unroll
  for (int t = 0; t < 3; ++t) { issueA(t); issueB(t); }

#pragma unroll 1
  for (int t = 0; t < KT32; ++t) {
    const int so = (t & 3) * SLOTB;
    // counted wait: own loads of tile t done; up to 8 younger stay in flight
    if (t < KT32 - 2)       asm volatile("s_waitcnt vmcnt(8)" ::: "memory");
    else if (t == KT32 - 2) asm volatile("s_waitcnt vmcnt(4)" ::: "memory");
    else                    asm volatile("s_waitcnt vmcnt(0)" ::: "memory");
    __builtin_amdgcn_sched_barrier(0);
    __builtin_amdgcn_s_barrier();   // collective: every wave's tile-t loads in

    // ALL 12 fragment reads issued up front. Pinned order: {bf0-3, af0-3}
    // first, sched_barrier, then {af4-7} -- so counted lgkmcnt(4) is exact.
    v8s bf[4], af[8];
#pragma unroll
    for (int nt = 0; nt < 4; ++nt) bf[nt] = *(const v8s*)(bR + so + nt * 1024 + cA);
#pragma unroll
    for (int i = 0; i < 4; ++i)    af[i] = *(const v8s*)(aR + so + i * 1024 + cA);
    __builtin_amdgcn_sched_barrier(0);  // DS order fence: first 8 before last 4
#pragma unroll
    for (int i = 4; i < 8; ++i)    af[i] = *(const v8s*)(aR + so + i * 1024 + cA);
    // next-tile staging (vmcnt-counted, order A then B preserved per tile)
    if (t + 3 < KT32) { issueA(t + 3); issueB(t + 3); }

    asm volatile("s_waitcnt lgkmcnt(4)" ::: "memory");  // bf0-3 + af0-3 done
    __builtin_amdgcn_sched_barrier(0);                  // rule #18
    __builtin_amdgcn_s_setprio(1);
#pragma unroll
    for (int i = 0; i < 4; ++i)
#pragma unroll
      for (int nt = 0; nt < 4; ++nt)
        acc[i][nt] = __builtin_amdgcn_mfma_f32_16x16x32_bf16(af[i], bf[nt], acc[i][nt], 0, 0, 0);
    asm volatile("s_waitcnt lgkmcnt(0)" ::: "memory");  // af4-7 (hid under MFMA)
    __builtin_amdgcn_sched_barrier(0);
#pragma unroll
    for (int i = 0; i < 4; ++i)
#pragma unroll
      for (int nt = 0; nt < 4; ++nt)
        acc[4 + i][nt] = __builtin_amdgcn_mfma_f32_16x16x32_bf16(af[4 + i], bf[nt], acc[4 + i][nt], 0, 0, 0);
    __builtin_amdgcn_s_setprio(0);
    // no mid/trailing barrier: next tile's top vmcnt+barrier realigns waves.
    // slot-reuse safety: each wave's reads of tile t complete (lgkmcnt(0))
    // before it reaches tile t+1's barrier; loads(t+4) issue after it.
  }

  // epilogue: C/D layout col=lm, row=quad*4+r (dtype-independent, m89/m91)
  if (bn0 < 768) {
#pragma unroll
    for (int mt = 0; mt < 8; ++mt)
#pragma unroll
      for (int nt = 0; nt < 4; ++nt) {
        const int col = bn0 + wcol * 64 + nt * 16 + lm;
        const float bs = bias[col];
        const int grow0 = bm0 + wrow * 128 + mt * 16 + quad * 4;
#pragma unroll
        for (int r = 0; r < 4; ++r)
          kp_[(size_t)(grow0 + r) * 768 + col] = f2bf(acc[mt][nt][r] + bs);
      }
  } else {
#pragma unroll
    for (int mt = 0; mt < 8; ++mt)
#pragma unroll
      for (int nt = 0; nt < 4; ++nt) {
        const int col = bn0 + wcol * 64 + nt * 16 + lm;
        const int cv = col - 768;
        const float bs = bias[col];
        const int grow0 = bm0 + wrow * 128 + mt * 16 + quad * 4;
        const int b_ = grow0 >> 12, kvr = grow0 & 4095;
        uint2 o;
        o.x = pack2(acc[mt][nt][0] + bs, acc[mt][nt][1] + bs);
        o.y = pack2(acc[mt][nt][2] + bs, acc[mt][nt][3] + bs);
        *(uint2*)&vT_[((size_t)(b_ * 768 + cv)) * 4096 + kvr] = o;
      }
  }
}

// block = (b, h, 16-row q slab); 4 waves, wave w covers kv rows [w*1024, w*1024+1024)
// partial (m,l,O) combined across waves in LDS at the end.
__global__ __launch_bounds__(256) void attn_k(
    const u16* __restrict__ qp,  // (B*64, 768) bf16
    const u16* __restrict__ kp,  // (B*4096, 768) bf16
    const u16* __restrict__ vT,  // (B*768, 4096) bf16: row b*768+h*64+d, col kv
    u16* __restrict__ xo)        // (B*64, 768) bf16
{
  __shared__ __align__(16) u16 Ps[4][16][40];
  __shared__ float Mw[4][16], Lw[4][16];
  __shared__ float Os[4][16][64];
  const int lane = threadIdx.x & 63, w = threadIdx.x >> 6;
  const int lm = lane & 15, quad = lane >> 4;
  const int blk = blockIdx.x, slab = blk & 3, bh = blk >> 2;
  const int b = bh / NH, h = bh - b * NH;
  const int qr0 = b * NQ + slab * 16;

  const u16* qptr = qp + (size_t)(qr0 + lm) * QD + h * HD + quad * 8;
  v8s aq0 = *(const v8s*)qptr;
  v8s aq1 = *(const v8s*)(qptr + 32);

  const u16* kb = kp + (size_t)b * NKV * QD + h * HD;
  const u16* vb = vT + (size_t)(b * QD + h * HD) * NKV;

  float mst[4], lst[4];
  v4f O[4];
  v4f zero = {0.f, 0.f, 0.f, 0.f};
#pragma unroll
  for (int r = 0; r < 4; ++r) { mst[r] = -INFINITY; lst[r] = 0.f; }
#pragma unroll
  for (int d = 0; d < 4; ++d) O[d] = zero;

  const float scale = 0.125f;

  v8s kf[2][4], vf[2][4];
  auto loadchunk = [&](int j0, int bi) {
    const u16* k0p = kb + (size_t)(j0 + lm) * QD + quad * 8;
    const u16* k1p = kb + (size_t)(j0 + 16 + lm) * QD + quad * 8;
    kf[bi][0] = *(const v8s*)k0p;
    kf[bi][1] = *(const v8s*)(k0p + 32);
    kf[bi][2] = *(const v8s*)k1p;
    kf[bi][3] = *(const v8s*)(k1p + 32);
#pragma unroll
    for (int d = 0; d < 4; ++d)
      vf[bi][d] = *(const v8s*)&vb[(size_t)(d * 16 + lm) * NKV + j0 + quad * 8];
  };
  auto compute = [&](int bi) {
    v4f S0 = zero, S1 = zero;
    S0 = __builtin_amdgcn_mfma_f32_16x16x32_bf16(aq0, kf[bi][0], S0, 0, 0, 0);
    S0 = __builtin_amdgcn_mfma_f32_16x16x32_bf16(aq1, kf[bi][1], S0, 0, 0, 0);
    S1 = __builtin_amdgcn_mfma_f32_16x16x32_bf16(aq0, kf[bi][2], S1, 0, 0, 0);
    S1 = __builtin_amdgcn_mfma_f32_16x16x32_bf16(aq1, kf[bi][3], S1, 0, 0, 0);

    float p0[4], p1[4], rmax[4];
#pragma unroll
    for (int r = 0; r < 4; ++r) {
      p0[r] = S0[r] * scale; p1[r] = S1[r] * scale;
      rmax[r] = fmaxf(p0[r], p1[r]);
    }
#pragma unroll
    for (int off = 1; off <= 8; off <<= 1)
#pragma unroll
      for (int r = 0; r < 4; ++r) rmax[r] = fmaxf(rmax[r], __shfl_xor(rmax[r], off, 64));

    float alpha[4], rsum[4];
#pragma unroll
    for (int r = 0; r < 4; ++r) {
      float mn = fmaxf(mst[r], rmax[r]);
      alpha[r] = __expf(mst[r] - mn);
      p0[r] = __expf(p0[r] - mn);
      p1[r] = __expf(p1[r] - mn);
      mst[r] = mn;
      rsum[r] = p0[r] + p1[r];
    }
#pragma unroll
    for (int off = 1; off <= 8; off <<= 1)
#pragma unroll
      for (int r = 0; r < 4; ++r) rsum[r] += __shfl_xor(rsum[r], off, 64);
#pragma unroll
    for (int r = 0; r < 4; ++r) {
      lst[r] = lst[r] * alpha[r] + rsum[r];
      Ps[w][quad * 4 + r][lm] = f2bf(p0[r]);
      Ps[w][quad * 4 + r][16 + lm] = f2bf(p1[r]);
    }
#pragma unroll
    for (int d = 0; d < 4; ++d)
#pragma unroll
      for (int r = 0; r < 4; ++r) O[d][r] *= alpha[r];
    v8s aP = *(const v8s*)&Ps[w][lm][quad * 8];  // single-wave DS: in-order
#pragma unroll
    for (int d = 0; d < 4; ++d)
      O[d] = __builtin_amdgcn_mfma_f32_16x16x32_bf16(aP, vf[bi][d], O[d], 0, 0, 0);
  };

  const int base = w * 1024;
  loadchunk(base, 0);
  for (int j0 = base; j0 < base + 1024; j0 += 64) {
    loadchunk(j0 + 32, 1);
    compute(0);
    if (j0 + 64 < base + 1024) loadchunk(j0 + 64, 0);
    compute(1);
  }

  // cross-wave online-softmax combine
  if (lm == 0) {
#pragma unroll
    for (int r = 0; r < 4; ++r) {
      Mw[w][quad * 4 + r] = mst[r];
      Lw[w][quad * 4 + r] = lst[r];
    }
  }
  __syncthreads();
#pragma unroll
  for (int r = 0; r < 4; ++r) {
    int row = quad * 4 + r;
    float M = fmaxf(fmaxf(Mw[0][row], Mw[1][row]), fmaxf(Mw[2][row], Mw[3][row]));
    float sc = __expf(mst[r] - M);
#pragma unroll
    for (int d = 0; d < 4; ++d) Os[w][row][d * 16 + lm] = O[d][r] * sc;
  }
  __syncthreads();
#pragma unroll
  for (int i = 0; i < 4; ++i) {
    int row = w * 4 + i;
    float M = fmaxf(fmaxf(Mw[0][row], Mw[1][row]), fmaxf(Mw[2][row], Mw[3][row]));
    float L = Lw[0][row] * __expf(Mw[0][row] - M) + Lw[1][row] * __expf(Mw[1][row] - M)
            + Lw[2][row] * __expf(Mw[2][row] - M) + Lw[3][row] * __expf(Mw[3][row] - M);
    float o = Os[0][row][lane] + Os[1][row][lane] + Os[2][row][lane] + Os[3][row][lane];
    xo[(size_t)(qr0 + row) * QD + h * HD + lane] = f2bf(o / L);
  }
}

extern "C" void kernel_launch(void* const* d_in, const int* in_sizes, int n_in,
                              void* d_out, int out_size, void* d_ws, size_t ws_size,
                              hipStream_t stream) {
  const float* query = (const float*)d_in[0];
  const float* kv    = (const float*)d_in[1];
  const float* Wq    = (const float*)d_in[2];
  const float* bq    = (const float*)d_in[3];
  const float* Wk    = (const float*)d_in[4];
  const float* bk    = (const float*)d_in[5];
  const float* Wv    = (const float*)d_in[6];
  const float* bv    = (const float*)d_in[7];
  const float* Wo    = (const float*)d_in[8];
  const float* bo    = (const float*)d_in[9];
  float* out = (float*)d_out;
  char* ws = (char*)d_ws;

  // ws layout (bytes); total used: 345,774,080
  u16*   WkvT = (u16*)(ws);                   // (1536,1024)      3,145,728
  float* bkv  = (float*)(ws + 3145728);       // 1536 f32             6,144
  u16*   WqT  = (u16*)(ws + 3151872);         // (768,768)        1,179,648
  u16*   WoT  = (u16*)(ws + 4331520);         //                  1,179,648
  u16*   qbf  = (u16*)(ws + 5511168);         // (1024,768)       1,572,864
  u16*   qp   = (u16*)(ws + 7084032);         // (1024,768)       1,572,864
  u16*   xov  = (u16*)(ws + 8656896);         // (1024,768)       1,572,864
  u16*   kp   = (u16*)(ws + 10229760);        // (65536,768)    100,663,296
  u16*   vT   = (u16*)(ws + 110893056);       // (16*768,4096)  100,663,296
  u16*   kvbf = (u16*)(ws + 211556352);       // (65536,1024)   134,217,728

  prep_wT_dual<<<dim3(24, 32, 2), 256, 0, stream>>>(Wk, Wv, WkvT, WkvT + 768 * 1024, KD, QD);
  prep_wT_dual<<<dim3(24, 24, 2), 256, 0, stream>>>(Wq, Wo, WqT, WoT, QD, QD);
  concat_bias<<<6, 256, 0, stream>>>(bk, bv, bkv);
  // full kv f32 -> bf16 (one pass)
  conv8<<<32768, 256, 0, stream>>>(kv, kvbf, NB * NKV * KD / 8);
  // fused k+v projection: 256x256-tile, 4-slot deep-pipelined GEMM
  // (65536,1024) @ (1024,1536) -> kp + transposed vT ; 1536 blocks = 6x256 tiles
  gemm_kv256<<<1536, 512, 0, stream>>>(kvbf, WkvT, bkv, kp, vT);
  // q conversion + projection
  conv8<<<384, 256, 0, stream>>>(query, qbf, NB * NQ * QD / 8);
  gemm_a<true, false><<<dim3(6, 8), 256, 0, stream>>>(qbf, WqT, bq, qp, nullptr,
                                                      1024, QD, QD);
  // attention: block=(b,h,slab), 4 waves kv-split + LDS combine
  attn_k<<<NB * NH * 4, 256, 0, stream>>>(qp, kp, vT, xov);
  // output projection -> f32
  gemm_a<false, false><<<dim3(6, 8), 256, 0, stream>>>(xov, WoT, bo, out, nullptr,
                                                       1024, QD, QD);
}